// Round 2
// baseline (151.123 us; speedup 1.0000x reference)
//
#include <hip/hip_runtime.h>

// EdgeLoss: mean |sobel_edge(pred) - sobel_edge(target)| over [16,3,512,512] fp32.
// Depthwise 3x3 Sobel (zero pad), edge = sqrt(gx^2+gy^2+1e-6).
// Sign of Sobel orientation is irrelevant (enters via squares), so
// convolution-vs-correlation flip doesn't matter.

#define EW 512
#define EH 512
#define EPLANE (EH * EW)          // 262144
#define NPLANES 48                // 2*8 images * 3 channels
#define TOTAL_PX (NPLANES * EPLANE) // 12582912
#define STRIPS_PER_PLANE (EPLANE / 4)   // 65536
#define BLOCKS_MAIN (TOTAL_PX / 4 / 256) // 12288

__device__ __forceinline__ void load_row6(const float* __restrict__ row, int x0,
                                          bool valid, float* a) {
    if (!valid) {
        a[0] = a[1] = a[2] = a[3] = a[4] = a[5] = 0.f;
        return;
    }
    a[0] = (x0 > 0) ? row[x0 - 1] : 0.f;
    float4 c = *reinterpret_cast<const float4*>(row + x0);
    a[1] = c.x; a[2] = c.y; a[3] = c.z; a[4] = c.w;
    a[5] = (x0 + 4 < EW) ? row[x0 + 4] : 0.f;
}

__global__ __launch_bounds__(256) void edge_main(const float* __restrict__ pred,
                                                 const float* __restrict__ tgt,
                                                 float* __restrict__ partial) {
    const int t = blockIdx.x * 256 + threadIdx.x;   // strip index, exact cover
    const int plane = t >> 16;                      // 65536 strips per plane
    const int s = t & 65535;
    const int y = s >> 7;                           // 128 strips per row
    const int x0 = (s & 127) << 2;

    const float* __restrict__ prow = pred + plane * EPLANE + y * EW;
    const float* __restrict__ qrow = tgt  + plane * EPLANE + y * EW;
    const bool ymv = (y > 0);
    const bool ypv = (y < EH - 1);

    float pt[6], pm[6], pb[6], tt[6], tm[6], tb[6];
    load_row6(prow - EW, x0, ymv, pt);
    load_row6(prow,      x0, true, pm);
    load_row6(prow + EW, x0, ypv, pb);
    load_row6(qrow - EW, x0, ymv, tt);
    load_row6(qrow,      x0, true, tm);
    load_row6(qrow + EW, x0, ypv, tb);

    float sum = 0.f;
#pragma unroll
    for (int i = 0; i < 4; ++i) {
        float gxp = (pt[i+2] - pt[i]) + 2.f * (pm[i+2] - pm[i]) + (pb[i+2] - pb[i]);
        float gyp = (pb[i] - pt[i]) + 2.f * (pb[i+1] - pt[i+1]) + (pb[i+2] - pt[i+2]);
        float ep  = sqrtf(gxp * gxp + gyp * gyp + 1e-6f);
        float gxt = (tt[i+2] - tt[i]) + 2.f * (tm[i+2] - tm[i]) + (tb[i+2] - tb[i]);
        float gyt = (tb[i] - tt[i]) + 2.f * (tb[i+1] - tt[i+1]) + (tb[i+2] - tt[i+2]);
        float et  = sqrtf(gxt * gxt + gyt * gyt + 1e-6f);
        sum += fabsf(ep - et);
    }

    // wave-64 shuffle reduce
    for (int off = 32; off > 0; off >>= 1)
        sum += __shfl_down(sum, off, 64);

    __shared__ float wsum[4];
    const int lane = threadIdx.x & 63;
    const int wid  = threadIdx.x >> 6;
    if (lane == 0) wsum[wid] = sum;
    __syncthreads();
    if (threadIdx.x == 0)
        partial[blockIdx.x] = wsum[0] + wsum[1] + wsum[2] + wsum[3];
}

__global__ __launch_bounds__(256) void edge_final(const float* __restrict__ partial,
                                                  int n, float* __restrict__ out) {
    double s = 0.0;
    for (int i = threadIdx.x; i < n; i += 256) s += (double)partial[i];
    __shared__ double sd[256];
    sd[threadIdx.x] = s;
    __syncthreads();
    for (int k = 128; k > 0; k >>= 1) {
        if (threadIdx.x < k) sd[threadIdx.x] += sd[threadIdx.x + k];
        __syncthreads();
    }
    if (threadIdx.x == 0) out[0] = (float)(sd[0] / (double)TOTAL_PX);
}

extern "C" void kernel_launch(void* const* d_in, const int* in_sizes, int n_in,
                              void* d_out, int out_size, void* d_ws, size_t ws_size,
                              hipStream_t stream) {
    const float* pred = (const float*)d_in[0];
    const float* tgt  = (const float*)d_in[1];
    float* partial = (float*)d_ws;   // BLOCKS_MAIN floats (48 KB) of scratch
    float* out = (float*)d_out;

    edge_main<<<BLOCKS_MAIN, 256, 0, stream>>>(pred, tgt, partial);
    edge_final<<<1, 256, 0, stream>>>(partial, BLOCKS_MAIN, out);
}

// Round 3
// 123.980 us; speedup vs baseline: 1.2189x; 1.2189x over previous
//
#include <hip/hip_runtime.h>

// EdgeLoss: mean |sobel_edge(pred) - sobel_edge(target)| over [16,3,512,512] fp32.
// Depthwise 3x3 Sobel (zero pad), edge = sqrt(gx^2+gy^2+1e-6).
// Each thread: 4-wide x 8-tall tile, rolling 3-row register window.

#define EW 512
#define EH 512
#define EPLANE (EH * EW)               // 262144
#define NPLANES 48                     // 2*8 images * 3 channels
#define TOTAL_PX (NPLANES * EPLANE)    // 12582912
#define ROWS_PT 8
#define THREADS_TOTAL (TOTAL_PX / (4 * ROWS_PT))  // 393216
#define BLOCKS_MAIN (THREADS_TOTAL / 256)         // 1536

__device__ __forceinline__ void load_row6(float* a, const float* __restrict__ row,
                                          int x0, bool valid) {
    if (valid) {
        float4 c = *reinterpret_cast<const float4*>(row + x0);
        a[1] = c.x; a[2] = c.y; a[3] = c.z; a[4] = c.w;
        a[0] = (x0 > 0)      ? row[x0 - 1] : 0.f;
        a[5] = (x0 + 4 < EW) ? row[x0 + 4] : 0.f;
    } else {
        a[0] = a[1] = a[2] = a[3] = a[4] = a[5] = 0.f;
    }
}

__global__ __launch_bounds__(256) void edge_main(const float* __restrict__ pred,
                                                 const float* __restrict__ tgt,
                                                 float* __restrict__ partial) {
    const int t = blockIdx.x * 256 + threadIdx.x;   // 0..393215
    const int plane = t >> 13;                      // 8192 threads per plane
    const int s = t & 8191;
    const int band = s >> 7;                        // 64 bands of 8 rows
    const int x0 = (s & 127) << 2;                  // 128 strips of 4 cols
    const int y0 = band << 3;

    const float* __restrict__ prow = pred + plane * EPLANE + y0 * EW;
    const float* __restrict__ qrow = tgt  + plane * EPLANE + y0 * EW;

    float P[3][6], T[3][6];
    load_row6(P[0], prow - EW, x0, y0 > 0);
    load_row6(T[0], qrow - EW, x0, y0 > 0);
    load_row6(P[1], prow,      x0, true);
    load_row6(T[1], qrow,      x0, true);

    float sum = 0.f;
#pragma unroll
    for (int r = 0; r < ROWS_PT; ++r) {
        // window: top = row y0+r-1, mid = y0+r, bot = y0+r+1
        float (&Pt)[6] = P[r % 3];
        float (&Pm)[6] = P[(r + 1) % 3];
        float (&Pb)[6] = P[(r + 2) % 3];
        float (&Tt)[6] = T[r % 3];
        float (&Tm)[6] = T[(r + 1) % 3];
        float (&Tb)[6] = T[(r + 2) % 3];
        const bool bot_valid = (y0 + r + 1) < EH;   // wave-uniform
        load_row6(Pb, prow + (r + 1) * EW, x0, bot_valid);
        load_row6(Tb, qrow + (r + 1) * EW, x0, bot_valid);
#pragma unroll
        for (int i = 0; i < 4; ++i) {
            float gxp = (Pt[i+2] - Pt[i]) + 2.f * (Pm[i+2] - Pm[i]) + (Pb[i+2] - Pb[i]);
            float gyp = (Pb[i] - Pt[i]) + 2.f * (Pb[i+1] - Pt[i+1]) + (Pb[i+2] - Pt[i+2]);
            float ep  = sqrtf(gxp * gxp + gyp * gyp + 1e-6f);
            float gxt = (Tt[i+2] - Tt[i]) + 2.f * (Tm[i+2] - Tm[i]) + (Tb[i+2] - Tb[i]);
            float gyt = (Tb[i] - Tt[i]) + 2.f * (Tb[i+1] - Tt[i+1]) + (Tb[i+2] - Tt[i+2]);
            float et  = sqrtf(gxt * gxt + gyt * gyt + 1e-6f);
            sum += fabsf(ep - et);
        }
    }

    // wave-64 shuffle reduce
    for (int off = 32; off > 0; off >>= 1)
        sum += __shfl_down(sum, off, 64);

    __shared__ float wsum[4];
    const int lane = threadIdx.x & 63;
    const int wid  = threadIdx.x >> 6;
    if (lane == 0) wsum[wid] = sum;
    __syncthreads();
    if (threadIdx.x == 0)
        partial[blockIdx.x] = wsum[0] + wsum[1] + wsum[2] + wsum[3];
}

__global__ __launch_bounds__(256) void edge_final(const float* __restrict__ partial,
                                                  int n, float* __restrict__ out) {
    double s = 0.0;
    for (int i = threadIdx.x; i < n; i += 256) s += (double)partial[i];
    __shared__ double sd[256];
    sd[threadIdx.x] = s;
    __syncthreads();
    for (int k = 128; k > 0; k >>= 1) {
        if (threadIdx.x < k) sd[threadIdx.x] += sd[threadIdx.x + k];
        __syncthreads();
    }
    if (threadIdx.x == 0) out[0] = (float)(sd[0] / (double)TOTAL_PX);
}

extern "C" void kernel_launch(void* const* d_in, const int* in_sizes, int n_in,
                              void* d_out, int out_size, void* d_ws, size_t ws_size,
                              hipStream_t stream) {
    const float* pred = (const float*)d_in[0];
    const float* tgt  = (const float*)d_in[1];
    float* partial = (float*)d_ws;   // BLOCKS_MAIN floats of scratch
    float* out = (float*)d_out;

    edge_main<<<BLOCKS_MAIN, 256, 0, stream>>>(pred, tgt, partial);
    edge_final<<<1, 256, 0, stream>>>(partial, BLOCKS_MAIN, out);
}

// Round 4
// 121.156 us; speedup vs baseline: 1.2473x; 1.0233x over previous
//
#include <hip/hip_runtime.h>

// EdgeLoss: mean |sobel_edge(pred) - sobel_edge(target)| over [16,3,512,512] fp32.
// Depthwise 3x3 Sobel (zero pad), edge = sqrt(gx^2+gy^2+1e-6).
// Each thread: 4-wide x 8-tall tile; 4-slot circular row buffer with
// distance-1 prefetch (loads for row r+2 issued while computing row r);
// fast hardware sqrt (v_sqrt_f32).

#define EW 512
#define EH 512
#define EPLANE (EH * EW)               // 262144
#define NPLANES 48                     // 2*8 images * 3 channels
#define TOTAL_PX (NPLANES * EPLANE)    // 12582912
#define ROWS_PT 8
#define THREADS_TOTAL (TOTAL_PX / (4 * ROWS_PT))  // 393216
#define BLOCKS_MAIN (THREADS_TOTAL / 256)         // 1536

__device__ __forceinline__ void load_row6(float* a, const float* __restrict__ row,
                                          int x0, bool valid) {
    if (valid) {
        float4 c = *reinterpret_cast<const float4*>(row + x0);
        a[1] = c.x; a[2] = c.y; a[3] = c.z; a[4] = c.w;
        a[0] = (x0 > 0)      ? row[x0 - 1] : 0.f;
        a[5] = (x0 + 4 < EW) ? row[x0 + 4] : 0.f;
    } else {
        a[0] = a[1] = a[2] = a[3] = a[4] = a[5] = 0.f;
    }
}

__global__ __launch_bounds__(256) void edge_main(const float* __restrict__ pred,
                                                 const float* __restrict__ tgt,
                                                 float* __restrict__ partial) {
    const int t = blockIdx.x * 256 + threadIdx.x;   // 0..393215
    const int plane = t >> 13;                      // 8192 threads per plane
    const int s = t & 8191;
    const int y0 = ((s >> 7) & 63) << 3;            // band of 8 rows
    const int x0 = (s & 127) << 2;                  // 4-col strip

    const float* __restrict__ prow = pred + plane * EPLANE + y0 * EW;
    const float* __restrict__ qrow = tgt  + plane * EPLANE + y0 * EW;

    // circular buffer: row offset k in [-1, 8] lives in slot (k+1)&3
    float P[4][6], T[4][6];
    load_row6(P[0], prow - EW, x0, y0 > 0);   // k=-1
    load_row6(T[0], qrow - EW, x0, y0 > 0);
    load_row6(P[1], prow,      x0, true);     // k=0
    load_row6(T[1], qrow,      x0, true);
    load_row6(P[2], prow + EW, x0, true);     // k=1 (y0+1 <= 505 < 512 always)
    load_row6(T[2], qrow + EW, x0, true);

    float sum = 0.f;
#pragma unroll
    for (int r = 0; r < ROWS_PT; ++r) {
        // prefetch row k=r+2 into slot (r+3)&3 (consumed at iteration r+1)
        if (r < ROWS_PT - 1) {
            const bool v = (y0 + r + 2) < EH;   // wave-uniform
            load_row6(P[(r + 3) & 3], prow + (r + 2) * EW, x0, v);
            load_row6(T[(r + 3) & 3], qrow + (r + 2) * EW, x0, v);
        }
        float (&Pt)[6] = P[r & 3];          // k=r-1
        float (&Pm)[6] = P[(r + 1) & 3];    // k=r
        float (&Pb)[6] = P[(r + 2) & 3];    // k=r+1
        float (&Tt)[6] = T[r & 3];
        float (&Tm)[6] = T[(r + 1) & 3];
        float (&Tb)[6] = T[(r + 2) & 3];
#pragma unroll
        for (int i = 0; i < 4; ++i) {
            float gxp = (Pt[i+2] - Pt[i]) + 2.f * (Pm[i+2] - Pm[i]) + (Pb[i+2] - Pb[i]);
            float gyp = (Pb[i] - Pt[i]) + 2.f * (Pb[i+1] - Pt[i+1]) + (Pb[i+2] - Pt[i+2]);
            float ep  = __builtin_amdgcn_sqrtf(gxp * gxp + gyp * gyp + 1e-6f);
            float gxt = (Tt[i+2] - Tt[i]) + 2.f * (Tm[i+2] - Tm[i]) + (Tb[i+2] - Tb[i]);
            float gyt = (Tb[i] - Tt[i]) + 2.f * (Tb[i+1] - Tt[i+1]) + (Tb[i+2] - Tt[i+2]);
            float et  = __builtin_amdgcn_sqrtf(gxt * gxt + gyt * gyt + 1e-6f);
            sum += fabsf(ep - et);
        }
    }

    // wave-64 shuffle reduce
    for (int off = 32; off > 0; off >>= 1)
        sum += __shfl_down(sum, off, 64);

    __shared__ float wsum[4];
    const int lane = threadIdx.x & 63;
    const int wid  = threadIdx.x >> 6;
    if (lane == 0) wsum[wid] = sum;
    __syncthreads();
    if (threadIdx.x == 0)
        partial[blockIdx.x] = wsum[0] + wsum[1] + wsum[2] + wsum[3];
}

__global__ __launch_bounds__(256) void edge_final(const float* __restrict__ partial,
                                                  int n, float* __restrict__ out) {
    double s = 0.0;
    for (int i = threadIdx.x; i < n; i += 256) s += (double)partial[i];
    __shared__ double sd[256];
    sd[threadIdx.x] = s;
    __syncthreads();
    for (int k = 128; k > 0; k >>= 1) {
        if (threadIdx.x < k) sd[threadIdx.x] += sd[threadIdx.x + k];
        __syncthreads();
    }
    if (threadIdx.x == 0) out[0] = (float)(sd[0] / (double)TOTAL_PX);
}

extern "C" void kernel_launch(void* const* d_in, const int* in_sizes, int n_in,
                              void* d_out, int out_size, void* d_ws, size_t ws_size,
                              hipStream_t stream) {
    const float* pred = (const float*)d_in[0];
    const float* tgt  = (const float*)d_in[1];
    float* partial = (float*)d_ws;   // BLOCKS_MAIN floats of scratch
    float* out = (float*)d_out;

    edge_main<<<BLOCKS_MAIN, 256, 0, stream>>>(pred, tgt, partial);
    edge_final<<<1, 256, 0, stream>>>(partial, BLOCKS_MAIN, out);
}